// Round 6
// baseline (2698.604 us; speedup 1.0000x reference)
//
#include <hip/hip_runtime.h>

#define TC   50
#define BC   128
#define DXC  128
#define DYC  64
#define NMCC 100
#define XBS  136   // sU stride (shorts): Xbf [112][136] / XcT [128][136]
#define A1S  136   // acts1 stride (sA)
#define A2S  72    // acts2 stride (sB)
#define A3S  40    // acts3 stride (sC)
#define IVS  72
#define KTS  72
#define HPS  20    // banded HP stride (f32)
#define LBS  12    // band L stride (f32): [j][0]=rd, [j][1..9]=L[j+d][j]
#define ZSS  67    // z-scratch stride (f32)
#define W2S  136
#define W3S  72

typedef float f32x4 __attribute__((ext_vector_type(4)));
typedef short s16x8 __attribute__((ext_vector_type(8)));

__device__ __forceinline__ unsigned short f2bf(float x){
  unsigned int u = __float_as_uint(x);
  u += 0x7fffu + ((u >> 16) & 1u);
  return (unsigned short)(u >> 16);
}

__device__ __forceinline__ unsigned int pk2bf(float lo, float hi){
  unsigned int r;
  asm volatile("v_cvt_pk_bf16_f32 %0, %1, %2" : "=v"(r) : "v"(lo), "v"(hi));
  return r;
}

__device__ __forceinline__ f32x4 mfma16(s16x8 a, s16x8 b, f32x4 c){
  return __builtin_amdgcn_mfma_f32_16x16x32_bf16(a, b, c, 0, 0, 0);
}

__device__ __forceinline__ s16x8 packA8(const float* p){
  f32x4 a = *(const f32x4*)p;
  f32x4 c = *(const f32x4*)(p + 4);
  s16x8 r;
  r[0]=(short)f2bf(a[0]); r[1]=(short)f2bf(a[1]);
  r[2]=(short)f2bf(a[2]); r[3]=(short)f2bf(a[3]);
  r[4]=(short)f2bf(c[0]); r[5]=(short)f2bf(c[1]);
  r[6]=(short)f2bf(c[2]); r[7]=(short)f2bf(c[3]);
  return r;
}

__device__ __forceinline__ float gc_taper(int row, int col){
  int dd = row - col; if (dd < 0) dd = -dd;
  if (128 - dd < dd) dd = 128 - dd;
  double z = (double)dd / 5.0;
  double g = 0.0;
  if (z < 1.0){
    g = 1.0 - (5.0/3.0)*z*z + (5.0/8.0)*z*z*z + 0.5*z*z*z*z - 0.25*z*z*z*z*z;
  } else if (z < 2.0){
    g = 4.0 - 5.0*z + (5.0/3.0)*z*z + (5.0/8.0)*z*z*z - 0.5*z*z*z*z
        + (1.0/12.0)*z*z*z*z*z - 2.0/(3.0*z);
  }
  return (float)(g / 99.0);   // fold 1/(NMC-1)
}

// ---------------- gin: obs @ Wih^T + bih for all (t,b) ----------------
__global__ __launch_bounds__(256) void gin_kernel(const float* __restrict__ obs,
                          const float* __restrict__ Wih, const float* __restrict__ bih,
                          float* __restrict__ gin){
  __shared__ float xrow[64];
  int blk = blockIdx.x;
  int t = blk / BC, b = blk % BC;
  int tid = threadIdx.x;
  if (tid < 64) xrow[tid] = obs[(b*TC + t)*DYC + tid];
  __syncthreads();
  float s = bih[tid];
  #pragma unroll
  for (int k = 0; k < 64; k += 4){
    f32x4 wv = *(const f32x4*)&Wih[tid*64 + k];
    s += wv[0]*xrow[k] + wv[1]*xrow[k+1] + wv[2]*xrow[k+2] + wv[3]*xrow[k+3];
  }
  gin[blk*256 + tid] = s;
}

// ---------------- lstm: recurrent part + q heads + kl ----------------
__global__ __launch_bounds__(256,1) void lstm_kernel(const float* __restrict__ gin,
     const float* __restrict__ Whh,
     const float* __restrict__ Wm, const float* __restrict__ bm,
     const float* __restrict__ Wv, const float* __restrict__ bv,
     float* __restrict__ qmean, float* __restrict__ qstd, float* __restrict__ klp){
  __shared__ float h[64], cc[64], graw[256], red[128];
  int b = blockIdx.x, tid = threadIdx.x;
  float w[64];
  #pragma unroll
  for (int k = 0; k < 64; k += 4){
    f32x4 v = *(const f32x4*)&Whh[tid*64 + k];
    w[k]=v[0]; w[k+1]=v[1]; w[k+2]=v[2]; w[k+3]=v[3];
  }
  if (tid < 64){ h[tid] = 0.f; cc[tid] = 0.f; }
  __syncthreads();
  for (int t = 0; t < TC; ++t){
    float g = gin[(t*BC + b)*256 + tid];
    #pragma unroll
    for (int k = 0; k < 64; k += 4){
      f32x4 hv = *(const f32x4*)&h[k];
      g += hv[0]*w[k] + hv[1]*w[k+1] + hv[2]*w[k+2] + hv[3]*w[k+3];
    }
    graw[tid] = g;
    __syncthreads();
    if (tid < 64){
      float ig = 1.f/(1.f + expf(-graw[tid]));
      float fg = 1.f/(1.f + expf(-graw[64 + tid]));
      float gg = tanhf(graw[128 + tid]);
      float og = 1.f/(1.f + expf(-graw[192 + tid]));
      float cn = fg*cc[tid] + ig*gg;
      cc[tid] = cn;
      h[tid] = og*tanhf(cn);
    }
    __syncthreads();
  }
  if (tid < 128){
    float sm_ = bm[tid], sv_ = bv[tid];
    #pragma unroll
    for (int k = 0; k < 64; k += 4){
      f32x4 wmv = *(const f32x4*)&Wm[tid*64 + k];
      f32x4 wvv = *(const f32x4*)&Wv[tid*64 + k];
      f32x4 hv  = *(const f32x4*)&h[k];
      sm_ += wmv[0]*hv[0] + wmv[1]*hv[1] + wmv[2]*hv[2] + wmv[3]*hv[3];
      sv_ += wvv[0]*hv[0] + wvv[1]*hv[1] + wvv[2]*hv[2] + wvv[3]*hv[3];
    }
    float qv = ((sv_ > 20.f) ? sv_ : log1pf(expf(sv_))) + 1e-4f;
    qmean[b*DXC + tid] = sm_;
    qstd[b*DXC + tid]  = sqrtf(qv);
    red[tid] = 0.5f*(qv + sm_*sm_ - 1.f - logf(qv));
  }
  __syncthreads();
  if (tid == 0){
    float s = 0.f;
    for (int i = 0; i < 128; ++i) s += red[i];
    klp[b] = s;
  }
}

// ---------------- EnKF megakernel: one block (16 waves) per batch b ----------------
// wave w (w<8): column group w, m-tiles 0..3 (rows 0..63)
// wave w+8   : column group w, m-tiles 4..6 (rows 64..111)
__global__ __launch_bounds__(1024,4) void enkf_kernel(
    const float* __restrict__ obs,
    const float* __restrict__ W1, const float* __restrict__ b1g,
    const float* __restrict__ W2, const float* __restrict__ b2g,
    const float* __restrict__ W3, const float* __restrict__ b3g,
    const float* __restrict__ W4, const float* __restrict__ b4g,
    const float* __restrict__ eps0, const float* __restrict__ epss,
    const float* __restrict__ nsyg,
    const float* __restrict__ qmean, const float* __restrict__ qstd,
    float* __restrict__ out_means, float* __restrict__ llp)
{
  __shared__ unsigned short sU[128*XBS];   // Xbf [112][136] / XcT [128][136] / z-scratch f32
  __shared__ unsigned short sA[112*A1S];   // acts1 / KT
  __shared__ unsigned short sB[112*A2S];   // acts2 / innov
  __shared__ unsigned short sC[112*A3S];   // acts3
  __shared__ unsigned short sW2[64*W2S];   // W2 bf16 resident
  __shared__ unsigned short sW3[32*W3S];   // W3 bf16 resident
  __shared__ float sHPb[64*HPS];           // banded HP (linear part)
  __shared__ float sW9[9*12];              // wrap corner HP[o][119+w]
  __shared__ float sLb[64*LBS];            // band L; [j][0]=rd, [j][1..9]=L[j+d][j]
  __shared__ float sXm[DXC];
  __shared__ float sRv[DYC];
  __shared__ float sSc[4];
  __shared__ float sPart[2][DXC];          // per-half column partial sums

  const int b    = blockIdx.x;
  const int tid  = threadIdx.x;
  const int lane = tid & 63;
  const int wid  = tid >> 6;          // 0..15
  const int l15  = lane & 15;
  const int l4   = lane >> 4;

  const int cg   = wid & 7;                       // column group 0..7
  const int half = wid >> 3;                      // m-half: 0 -> m0..3, 1 -> m4..6
  const int colN = cg*16 + l15;
  const int mb   = half * 4;                      // m-tile base
  const int mc   = half ? 3 : 4;                  // m-tile count
  const int col2 = (wid & 3)*16 + l15;            // P2 col
  const int col3 = (wid & 1)*16 + l15;            // P3 col
  const int mb2  = (wid >> 2 & 3) * 2;            // P2 m-base
  const int mc2  = ((wid >> 2 & 3) == 3) ? 1 : 2; // P2 m-count
  const int mt3  = (wid >> 1) & 7;                // P3 m-tile (idle if 7)

  // ---- hoisted weight fragments (W1, W4 only; W2/W3 live in LDS) ----
  s16x8 w1f[4], w4f;
  #pragma unroll
  for (int kt = 0; kt < 4; ++kt) w1f[kt] = packA8(&W1[colN*128 + kt*32 + 8*l4]);
  w4f = packA8(&W4[colN*32 + 8*l4]);
  const float bb1 = b1g[colN], bb2 = b2g[col2], bb3 = b3g[col3], bb4 = b4g[colN];

  // ---- cov tile assignment: 12 tiles, wave w<12 takes tile w ----
  const int mtw = (int)((0x333222111000ull >> (4*wid)) & 15);
  const int ntw = (int)((0x432321210710ull >> (4*wid)) & 15);
  float tv[4];
  #pragma unroll
  for (int i = 0; i < 4; ++i)
    tv[i] = gc_taper(mtw*16 + 4*l4 + i, ntw*16 + l15);

  // ---- systolic chol lane constants: 55 slots (dk,dd), dk in [0,9], dd in [0,9-dk]
  int cdk = 10, cdd = 0;
  { int acc = 0;
    #pragma unroll
    for (int q = 0; q < 10; ++q){
      int cnt = 10 - q;
      if (lane >= acc && lane < acc + cnt){ cdk = q; cdd = lane - acc; }
      acc += cnt;
    } }
  const int ioff_s  = (cdk + cdd > 9) ? 0 : (cdk + cdd);
  const int dk_s    = (cdk > 9) ? 0 : cdk;
  int baseNext = (cdk + 1)*10 - ((cdk + 1)*cdk)/2;
  const int shsrc   = (baseNext + cdd >= 55) ? 0 : (baseNext + cdd);
  const bool enterSlot = (cdk + cdd == 9) && (cdk <= 9);
  const bool isCol0    = (cdk == 0);

  // ---- stage W2/W3 to LDS as bf16 ----
  for (int idx = tid; idx < 64*128; idx += 1024)
    sW2[(idx >> 7)*W2S + (idx & 127)] = f2bf(W2[idx]);
  for (int idx = tid; idx < 32*64; idx += 1024)
    sW3[(idx >> 6)*W3S + (idx & 63)] = f2bf(W3[idx]);

  // ---- x0 into registers + bf16 mirror (each wave its own m-tiles) ----
  float xreg[4][4];
  {
    float qm = qmean[b*DXC + colN], qs = qstd[b*DXC + colN];
    #pragma unroll
    for (int mm = 0; mm < 4; ++mm)
      #pragma unroll
      for (int i = 0; i < 4; ++i){
        xreg[mm][i] = 0.f;
        if (mm < mc){
          int row = (mb+mm)*16 + 4*l4 + i;
          if (row < NMCC){
            float v = qm + qs * eps0[((size_t)row*BC + b)*DXC + colN];
            xreg[mm][i] = v;
            sU[row*XBS + colN] = f2bf(v);
          }
        }
      }
  }
  for (int idx = tid; idx < 12*128; idx += 1024)
    sU[(100 + (idx >> 7))*XBS + (idx & 127)] = 0;

  // ---- prefetch eps for t=0 ----
  float ev[4][4];
  #pragma unroll
  for (int mm = 0; mm < 4; ++mm)
    #pragma unroll
    for (int i = 0; i < 4; ++i){
      ev[mm][i] = 0.f;
      if (mm < mc){
        int row = (mb+mm)*16 + 4*l4 + i;
        if (row < NMCC) ev[mm][i] = epss[((size_t)row*BC + b)*DXC + colN];
      }
    }
  __syncthreads();

  float llsum = 0.f;
  const f32x4 z4 = {0.f, 0.f, 0.f, 0.f};

  for (int t = 0; t < TC; ++t){
    float ldet_t = 0.f;

    // y loads issued early (col groups 0..3 of both halves)
    float y_r = 0.f, ypv = 0.f;
    if (cg < 4){
      y_r = obs[((size_t)b*TC + t)*DYC + colN];
      ypv = y_r + 0.1f*nsyg[((size_t)t*BC + b)*DYC + colN];
    }

    // ============ P1: MLP L1 (16-wave m-split) -> sA ============
    {
      f32x4 acc[4];
      #pragma unroll
      for (int mm = 0; mm < 4; ++mm) acc[mm] = z4;
      #pragma unroll
      for (int kt = 0; kt < 4; ++kt){
        #pragma unroll
        for (int mm = 0; mm < 4; ++mm){
          if (mm < mc){
            s16x8 af = *(const s16x8*)&sU[((mb+mm)*16 + l15)*XBS + kt*32 + 8*l4];
            acc[mm] = mfma16(af, w1f[kt], acc[mm]);
          }
        }
      }
      #pragma unroll
      for (int mm = 0; mm < 4; ++mm){
        if (mm < mc){
          #pragma unroll
          for (int i = 0; i < 4; ++i){
            int row = (mb+mm)*16 + 4*l4 + i;
            sA[row*A1S + colN] = f2bf(fmaxf(acc[mm][i] + bb1, 0.f));
          }
        }
      }
    }
    __syncthreads();

    // ============ P2: MLP L2 (16-wave, W2 from LDS) -> sB ============
    {
      f32x4 acc[2];
      acc[0] = z4; acc[1] = z4;
      #pragma unroll
      for (int kt = 0; kt < 4; ++kt){
        s16x8 bf = *(const s16x8*)&sW2[col2*W2S + kt*32 + 8*l4];
        #pragma unroll
        for (int mm = 0; mm < 2; ++mm){
          if (mm < mc2){
            s16x8 af = *(const s16x8*)&sA[((mb2+mm)*16 + l15)*A1S + kt*32 + 8*l4];
            acc[mm] = mfma16(af, bf, acc[mm]);
          }
        }
      }
      #pragma unroll
      for (int mm = 0; mm < 2; ++mm){
        if (mm < mc2){
          #pragma unroll
          for (int i = 0; i < 4; ++i){
            int row = (mb2+mm)*16 + 4*l4 + i;
            sB[row*A2S + col2] = f2bf(fmaxf(acc[mm][i] + bb2, 0.f));
          }
        }
      }
    }
    __syncthreads();

    // ============ P3: MLP L3 (16-wave, W3 from LDS) -> sC ============
    if (mt3 < 7){
      f32x4 acc = z4;
      #pragma unroll
      for (int kt = 0; kt < 2; ++kt){
        s16x8 bf = *(const s16x8*)&sW3[col3*W3S + kt*32 + 8*l4];
        s16x8 af = *(const s16x8*)&sB[(mt3*16 + l15)*A2S + kt*32 + 8*l4];
        acc = mfma16(af, bf, acc);
      }
      #pragma unroll
      for (int i = 0; i < 4; ++i){
        int row = mt3*16 + 4*l4 + i;
        sC[row*A3S + col3] = f2bf(fmaxf(acc[i] + bb3, 0.f));
      }
    }
    __syncthreads();

    // ============ P4: L4 + eps -> xreg (own m-tiles); partial col sums ============
    {
      f32x4 acc[4];
      #pragma unroll
      for (int mm = 0; mm < 4; ++mm) acc[mm] = z4;
      #pragma unroll
      for (int mm = 0; mm < 4; ++mm){
        if (mm < mc){
          s16x8 af = *(const s16x8*)&sC[((mb+mm)*16 + l15)*A3S + 8*l4];
          acc[mm] = mfma16(af, w4f, acc[mm]);
        }
      }
      float part = 0.f;
      #pragma unroll
      for (int mm = 0; mm < 4; ++mm)
        #pragma unroll
        for (int i = 0; i < 4; ++i){
          if (mm < mc){
            int row = (mb+mm)*16 + 4*l4 + i;
            if (row < NMCC){
              float v = acc[mm][i] + bb4 + 0.05f*ev[mm][i];
              xreg[mm][i] = v;
              part += v;
            } else xreg[mm][i] = 0.f;
          }
        }
      part += __shfl_xor(part, 16);
      part += __shfl_xor(part, 32);
      if (l4 == 0) sPart[half][colN] = part;
    }
    __syncthreads();

    // ============ P5: mean combine; rv; XcT pack; innov pack ============
    {
      float xm = (sPart[0][colN] + sPart[1][colN]) * 0.01f;
      if (tid < 128) sXm[tid] = (sPart[0][tid] + sPart[1][tid]) * 0.01f;
      if (wid < 4 && l4 == 0) sRv[colN] = y_r - xm;

      if (colN <= 72 || colN >= 119){
        #pragma unroll
        for (int mm = 0; mm < 4; ++mm){
          if (mm < mc){
            int gm = mb + mm;
            bool dead = (gm == 6) && (l4 > 0);     // rows 100..111
            float v0 = dead ? 0.f : xreg[mm][0] - xm;
            float v1 = dead ? 0.f : xreg[mm][1] - xm;
            float v2 = dead ? 0.f : xreg[mm][2] - xm;
            float v3 = dead ? 0.f : xreg[mm][3] - xm;
            uint2 pk;
            pk.x = pk2bf(v0, v1);
            pk.y = pk2bf(v2, v3);
            *(uint2*)&sU[colN*XBS + gm*16 + 4*l4] = pk;
          }
        }
        if (half){                                  // rows 112..127 zero
          uint2 zz; zz.x = 0u; zz.y = 0u;
          *(uint2*)&sU[colN*XBS + 112 + 4*l4] = zz;
        }
      }
      if (cg < 4){
        #pragma unroll
        for (int mm = 0; mm < 4; ++mm){
          if (mm < mc){
            #pragma unroll
            for (int i = 0; i < 4; ++i){
              int row = (mb+mm)*16 + 4*l4 + i;
              sB[row*IVS + colN] = (row < NMCC) ? f2bf(ypv - xreg[mm][i])
                                                : (unsigned short)0;
            }
          }
        }
      }
    }
    __syncthreads();

    // ============ P6: banded cov tiles (12 waves) ============
    if (wid < 12){
      f32x4 a1 = z4;
      #pragma unroll
      for (int kt = 0; kt < 4; ++kt){
        s16x8 fa = *(const s16x8*)&sU[(mtw*16 + l15)*XBS + kt*32 + 8*l4];
        s16x8 fb = *(const s16x8*)&sU[(ntw*16 + l15)*XBS + kt*32 + 8*l4];
        a1 = mfma16(fa, fb, a1);
      }
      #pragma unroll
      for (int i = 0; i < 4; ++i){
        int o = mtw*16 + 4*l4 + i, e = ntw*16 + l15;
        float v = a1[i] * tv[i];
        if (ntw != 7){
          int dd = e - o;
          if (dd >= -9 && dd <= 9) sHPb[o*HPS + dd + 9] = v;
        } else {
          int w = e - 119;
          if (w >= 0 && o <= w) sW9[o*12 + w] = v;
        }
      }
    }
    __syncthreads();

    // ============ P7: eps(t+1) prefetch (all waves) ; chol (w0) ============
    if (t + 1 < TC){
      #pragma unroll
      for (int mm = 0; mm < 4; ++mm){
        if (mm < mc){
          #pragma unroll
          for (int i = 0; i < 4; ++i){
            int row = (mb+mm)*16 + 4*l4 + i;
            if (row < NMCC)
              ev[mm][i] = epss[((size_t)((t+1)*NMCC + row)*BC + b)*DXC + colN];
          }
        }
      }
    }
    if (wid == 0){
      // register-systolic banded Cholesky, half-bandwidth 9
      float v = 0.f;
      if (cdk <= 9) v = sHPb[cdk*HPS + cdd + 9] + ((cdd == 0) ? 0.01f : 0.f);
      for (int j = 0; j < 64; ++j){
        float enter = 0.f;
        if (enterSlot && (j + 10 < 64))
          enter = sHPb[(j + 10 - cdd)*HPS + cdd + 9] + ((cdd == 0) ? 0.01f : 0.f);
        float upiv = __shfl(v, 0);
        float u1   = __shfl(v, ioff_s);
        float u2   = __shfl(v, dk_s);
        float rd   = rsqrtf(upiv);
        float rpiv = rd * rd;
        if (isCol0){
          sLb[j*LBS + cdd] = (cdd == 0) ? rd : v * rd;
        }
        if (lane == 0) ldet_t += 0.5f * logf(upiv);
        float vu = (cdk >= 1) ? v - u1*u2*rpiv : v;
        float vs = __shfl(vu, shsrc);
        v = enterSlot ? enter : vs;
      }
    }
    __syncthreads();

    // ============ P8: band solves (83 RHS) -> KT bf16, means, ll ============
    {
      float* zscr = (float*)sU;
      unsigned short* KT = (unsigned short*)sA;
      int c = tid;
      if (c < 83){
        int e = (c < 73) ? c : (c + 46);
        bool isr = (c == 82);
        float w0,w1,w2,w3,w4,w5,w6,w7,w8,w9;
        {
          float wi[10];
          #pragma unroll
          for (int d = 0; d < 10; ++d){
            float bv = 0.f;
            if (isr) bv = sRv[d];
            else if (c < 73){
              int idx = e - d + 9;
              if (idx >= 0 && idx <= 18) bv = sHPb[d*HPS + idx];
            } else {
              int ww = e - 119;
              if (d <= ww) bv = sW9[d*12 + ww];
            }
            wi[d] = bv;
          }
          w0=wi[0]; w1=wi[1]; w2=wi[2]; w3=wi[3]; w4=wi[4];
          w5=wi[5]; w6=wi[6]; w7=wi[7]; w8=wi[8]; w9=wi[9];
        }
        float z2l = 0.f;
        for (int j = 0; j < 64; ++j){
          f32x4 lb0 = *(const f32x4*)&sLb[j*LBS];
          f32x4 lb4 = *(const f32x4*)&sLb[j*LBS + 4];
          float2 l89 = *(const float2*)&sLb[j*LBS + 8];
          float z = w0 * lb0[0];
          zscr[c*ZSS + j] = z;
          z2l += z*z;
          w0 = w1 - lb0[1]*z; w1 = w2 - lb0[2]*z; w2 = w3 - lb0[3]*z;
          w3 = w4 - lb4[0]*z; w4 = w5 - lb4[1]*z; w5 = w6 - lb4[2]*z;
          w6 = w7 - lb4[3]*z; w7 = w8 - l89.x*z;  w8 = w9 - l89.y*z;
          int jn = j + 10;
          float bv = 0.f;
          if (isr){ if (jn < 64) bv = sRv[jn]; }
          else if (c < 73){
            if (jn < 64 && j >= e - 19 && j <= e - 1) bv = sHPb[jn*HPS + (e - j - 1)];
          }
          w9 = bv;
        }
        if (isr) sSc[0] = z2l;
        float x1=0.f,x2=0.f,x3=0.f,x4=0.f,x5=0.f,x6=0.f,x7=0.f,x8=0.f,x9=0.f;
        float macc = 0.f, xodd = 0.f;
        for (int j = 63; j >= 0; --j){
          f32x4 lb0 = *(const f32x4*)&sLb[j*LBS];
          f32x4 lb4 = *(const f32x4*)&sLb[j*LBS + 4];
          float2 l89 = *(const float2*)&sLb[j*LBS + 8];
          float acc = zscr[c*ZSS + j]
            - lb0[1]*x1 - lb0[2]*x2 - lb0[3]*x3
            - lb4[0]*x4 - lb4[1]*x5 - lb4[2]*x6 - lb4[3]*x7
            - l89.x*x8 - l89.y*x9;
          float xj = acc * lb0[0];
          if (!isr){
            macc += sRv[j]*xj;
            if (j & 1) xodd = xj;
            else *(unsigned int*)&KT[e*KTS + j] = pk2bf(xj, xodd);
          }
          x9=x8; x8=x7; x7=x6; x6=x5; x5=x4; x4=x3; x3=x2; x2=x1; x1=xj;
        }
        if (!isr) out_means[((size_t)t*BC + b)*DXC + e] = sXm[e] + macc;
      } else if (c < 129){
        int e = c - 10;                               // cols 73..118: K is zero
        out_means[((size_t)t*BC + b)*DXC + e] = sXm[e];
      }
    }
    __syncthreads();

    // ============ P10: ll ; update xreg += innov @ K ; rewrite Xbf ============
    if (tid == 0){
      llsum += -0.5f*sSc[0] - ldet_t - 58.812066f;    // 0.5*DY*log(2*pi)
    }
    {
      f32x4 uacc[4];
      #pragma unroll
      for (int mm = 0; mm < 4; ++mm) uacc[mm] = z4;
      if (cg != 5 && cg != 6){
        const unsigned short* KT = (const unsigned short*)sA;
        #pragma unroll
        for (int kt = 0; kt < 2; ++kt){
          s16x8 bf = *(const s16x8*)&KT[colN*KTS + kt*32 + 8*l4];
          #pragma unroll
          for (int mm = 0; mm < 4; ++mm){
            if (mm < mc){
              s16x8 af = *(const s16x8*)&sB[((mb+mm)*16 + l15)*IVS + kt*32 + 8*l4];
              uacc[mm] = mfma16(af, bf, uacc[mm]);
            }
          }
        }
      }
      bool upd = ((colN <= 72) || (colN >= 119)) && (cg != 5) && (cg != 6);
      #pragma unroll
      for (int mm = 0; mm < 4; ++mm){
        if (mm < mc){
          #pragma unroll
          for (int i = 0; i < 4; ++i){
            int row = (mb+mm)*16 + 4*l4 + i;
            if (row < NMCC){
              float xn = xreg[mm][i] + (upd ? uacc[mm][i] : 0.f);
              xreg[mm][i] = xn;
              sU[row*XBS + colN] = f2bf(xn);
            }
          }
        }
      }
    }
    __syncthreads();
  } // t loop

  if (tid == 0) llp[b] = llsum;
}

// ---------------- final: elbo = -mean(kl) + sum_t mean_b ll ----------------
__global__ void final_kernel(const float* __restrict__ klp, const float* __restrict__ llp,
                             float* __restrict__ out){
  __shared__ float s1[128], s2[128];
  int tid = threadIdx.x;
  s1[tid] = klp[tid];
  s2[tid] = llp[tid];
  __syncthreads();
  if (tid == 0){
    float a = 0.f, c = 0.f;
    for (int i = 0; i < 128; ++i){ a += s1[i]; c += s2[i]; }
    out[0] = -a/128.f + c/128.f;
  }
}

extern "C" void kernel_launch(void* const* d_in, const int* in_sizes, int n_in,
                              void* d_out, int out_size, void* d_ws, size_t ws_size,
                              hipStream_t stream){
  (void)in_sizes; (void)n_in; (void)out_size; (void)ws_size;
  const float* obs  = (const float*)d_in[0];
  const float* W1   = (const float*)d_in[1];
  const float* b1   = (const float*)d_in[2];
  const float* W2   = (const float*)d_in[3];
  const float* b2   = (const float*)d_in[4];
  const float* W3   = (const float*)d_in[5];
  const float* b3   = (const float*)d_in[6];
  const float* W4   = (const float*)d_in[7];
  const float* b4   = (const float*)d_in[8];
  const float* Wih  = (const float*)d_in[9];
  const float* Whh  = (const float*)d_in[10];
  const float* bih  = (const float*)d_in[11];
  const float* Wm   = (const float*)d_in[12];
  const float* bm   = (const float*)d_in[13];
  const float* Wv   = (const float*)d_in[14];
  const float* bv   = (const float*)d_in[15];
  const float* eps0 = (const float*)d_in[16];
  const float* epss = (const float*)d_in[17];
  const float* nsy  = (const float*)d_in[18];

  char* ws = (char*)d_ws;
  float* gin   = (float*)(ws + 0);           // 50*128*256*4 = 6,553,600 B
  float* qmean = (float*)(ws + 6553600);
  float* qstd  = (float*)(ws + 6619136);
  float* klp   = (float*)(ws + 6684672);
  float* llp   = (float*)(ws + 6685184);

  float* out = (float*)d_out;

  hipLaunchKernelGGL(gin_kernel, dim3(TC*BC), dim3(256), 0, stream,
                     obs, Wih, bih, gin);
  hipLaunchKernelGGL(lstm_kernel, dim3(BC), dim3(256), 0, stream,
                     gin, Whh, Wm, bm, Wv, bv, qmean, qstd, klp);
  hipLaunchKernelGGL(enkf_kernel, dim3(BC), dim3(1024), 0, stream,
                     obs, W1, b1, W2, b2, W3, b3, W4, b4,
                     eps0, epss, nsy, qmean, qstd, out + 1, llp);
  hipLaunchKernelGGL(final_kernel, dim3(1), dim3(128), 0, stream, klp, llp, out);
}

// Round 7
// 2040.297 us; speedup vs baseline: 1.3227x; 1.3227x over previous
//
#include <hip/hip_runtime.h>

#define TC   50
#define BC   128
#define DXC  128
#define DYC  64
#define NMCC 100
#define XBS  136   // sU stride (shorts): Xbf [112][136] / XcT [128][136]
#define A1S  136   // acts1 stride (sA)
#define A2S  72    // acts2 / innov stride (sB)
#define A3S  40    // acts3 stride (sC)
#define IVS  72
#define KTS  72
#define HPS  20    // banded HP stride (f32)
#define LBS  12    // band L stride (f32): [j][0]=rd, [j][1..9]=L[j+d][j]
#define ZSS  67    // z-scratch stride (f32)
#define W2S  136
#define W3S  72

typedef float f32x4 __attribute__((ext_vector_type(4)));
typedef short s16x8 __attribute__((ext_vector_type(8)));

__device__ __forceinline__ unsigned short f2bf(float x){
  unsigned int u = __float_as_uint(x);
  u += 0x7fffu + ((u >> 16) & 1u);
  return (unsigned short)(u >> 16);
}

__device__ __forceinline__ unsigned int pk2bf(float lo, float hi){
  unsigned int r;
  asm volatile("v_cvt_pk_bf16_f32 %0, %1, %2" : "=v"(r) : "v"(lo), "v"(hi));
  return r;
}

__device__ __forceinline__ f32x4 mfma16(s16x8 a, s16x8 b, f32x4 c){
  return __builtin_amdgcn_mfma_f32_16x16x32_bf16(a, b, c, 0, 0, 0);
}

__device__ __forceinline__ s16x8 packA8(const float* p){
  f32x4 a = *(const f32x4*)p;
  f32x4 c = *(const f32x4*)(p + 4);
  s16x8 r;
  r[0]=(short)f2bf(a[0]); r[1]=(short)f2bf(a[1]);
  r[2]=(short)f2bf(a[2]); r[3]=(short)f2bf(a[3]);
  r[4]=(short)f2bf(c[0]); r[5]=(short)f2bf(c[1]);
  r[6]=(short)f2bf(c[2]); r[7]=(short)f2bf(c[3]);
  return r;
}

__device__ __forceinline__ float gc_taper(int row, int col){
  int dd = row - col; if (dd < 0) dd = -dd;
  if (128 - dd < dd) dd = 128 - dd;
  double z = (double)dd / 5.0;
  double g = 0.0;
  if (z < 1.0){
    g = 1.0 - (5.0/3.0)*z*z + (5.0/8.0)*z*z*z + 0.5*z*z*z*z - 0.25*z*z*z*z*z;
  } else if (z < 2.0){
    g = 4.0 - 5.0*z + (5.0/3.0)*z*z + (5.0/8.0)*z*z*z - 0.5*z*z*z*z
        + (1.0/12.0)*z*z*z*z*z - 2.0/(3.0*z);
  }
  return (float)(g / 99.0);   // fold 1/(NMC-1)
}

// ---------------- gin: obs @ Wih^T + bih for all (t,b) ----------------
__global__ __launch_bounds__(256) void gin_kernel(const float* __restrict__ obs,
                          const float* __restrict__ Wih, const float* __restrict__ bih,
                          float* __restrict__ gin){
  __shared__ float xrow[64];
  int blk = blockIdx.x;
  int t = blk / BC, b = blk % BC;
  int tid = threadIdx.x;
  if (tid < 64) xrow[tid] = obs[(b*TC + t)*DYC + tid];
  __syncthreads();
  float s = bih[tid];
  #pragma unroll
  for (int k = 0; k < 64; k += 4){
    f32x4 wv = *(const f32x4*)&Wih[tid*64 + k];
    s += wv[0]*xrow[k] + wv[1]*xrow[k+1] + wv[2]*xrow[k+2] + wv[3]*xrow[k+3];
  }
  gin[blk*256 + tid] = s;
}

// ---------------- lstm: recurrent part + q heads + kl ----------------
__global__ __launch_bounds__(256,1) void lstm_kernel(const float* __restrict__ gin,
     const float* __restrict__ Whh,
     const float* __restrict__ Wm, const float* __restrict__ bm,
     const float* __restrict__ Wv, const float* __restrict__ bv,
     float* __restrict__ qmean, float* __restrict__ qstd, float* __restrict__ klp){
  __shared__ float h[64], cc[64], graw[256], red[128];
  int b = blockIdx.x, tid = threadIdx.x;
  float w[64];
  #pragma unroll
  for (int k = 0; k < 64; k += 4){
    f32x4 v = *(const f32x4*)&Whh[tid*64 + k];
    w[k]=v[0]; w[k+1]=v[1]; w[k+2]=v[2]; w[k+3]=v[3];
  }
  if (tid < 64){ h[tid] = 0.f; cc[tid] = 0.f; }
  __syncthreads();
  for (int t = 0; t < TC; ++t){
    float g = gin[(t*BC + b)*256 + tid];
    #pragma unroll
    for (int k = 0; k < 64; k += 4){
      f32x4 hv = *(const f32x4*)&h[k];
      g += hv[0]*w[k] + hv[1]*w[k+1] + hv[2]*w[k+2] + hv[3]*w[k+3];
    }
    graw[tid] = g;
    __syncthreads();
    if (tid < 64){
      float ig = 1.f/(1.f + expf(-graw[tid]));
      float fg = 1.f/(1.f + expf(-graw[64 + tid]));
      float gg = tanhf(graw[128 + tid]);
      float og = 1.f/(1.f + expf(-graw[192 + tid]));
      float cn = fg*cc[tid] + ig*gg;
      cc[tid] = cn;
      h[tid] = og*tanhf(cn);
    }
    __syncthreads();
  }
  if (tid < 128){
    float sm_ = bm[tid], sv_ = bv[tid];
    #pragma unroll
    for (int k = 0; k < 64; k += 4){
      f32x4 wmv = *(const f32x4*)&Wm[tid*64 + k];
      f32x4 wvv = *(const f32x4*)&Wv[tid*64 + k];
      f32x4 hv  = *(const f32x4*)&h[k];
      sm_ += wmv[0]*hv[0] + wmv[1]*hv[1] + wmv[2]*hv[2] + wmv[3]*hv[3];
      sv_ += wvv[0]*hv[0] + wvv[1]*hv[1] + wvv[2]*hv[2] + wvv[3]*hv[3];
    }
    float qv = ((sv_ > 20.f) ? sv_ : log1pf(expf(sv_))) + 1e-4f;
    qmean[b*DXC + tid] = sm_;
    qstd[b*DXC + tid]  = sqrtf(qv);
    red[tid] = 0.5f*(qv + sm_*sm_ - 1.f - logf(qv));
  }
  __syncthreads();
  if (tid == 0){
    float s = 0.f;
    for (int i = 0; i < 128; ++i) s += red[i];
    klp[b] = s;
  }
}

// ---------------- EnKF megakernel: one block (8 waves) per batch b ----------------
__global__ __launch_bounds__(512,1) void enkf_kernel(
    const float* __restrict__ obs,
    const float* __restrict__ W1, const float* __restrict__ b1g,
    const float* __restrict__ W2, const float* __restrict__ b2g,
    const float* __restrict__ W3, const float* __restrict__ b3g,
    const float* __restrict__ W4, const float* __restrict__ b4g,
    const float* __restrict__ eps0, const float* __restrict__ epss,
    const float* __restrict__ nsyg,
    const float* __restrict__ qmean, const float* __restrict__ qstd,
    float* __restrict__ out_means, float* __restrict__ llp)
{
  __shared__ unsigned short sU[128*XBS];   // Xbf [112][136] / XcT [128][136] / z-scratch f32
  __shared__ unsigned short sA[112*A1S];   // acts1 / KT
  __shared__ unsigned short sB[112*A2S];   // acts2 / innov
  __shared__ unsigned short sC[112*A3S];   // acts3
  __shared__ unsigned short sW2[64*W2S];   // W2 bf16 resident
  __shared__ unsigned short sW3[32*W3S];   // W3 bf16 resident
  __shared__ float sHPb[64*HPS];           // banded HP (linear part)
  __shared__ float sW9[9*12];              // wrap corner HP[o][119+w]
  __shared__ float sLb[64*LBS];            // band L; [j][0]=rd, [j][1..9]=L[j+d][j]
  __shared__ float sXm[DXC];
  __shared__ float sRv[DYC];
  __shared__ float sSc[4];

  const int b    = blockIdx.x;
  const int tid  = threadIdx.x;
  const int lane = tid & 63;
  const int wid  = tid >> 6;          // 0..7
  const int l15  = lane & 15;
  const int l4   = lane >> 4;

  const int colN = wid*16 + l15;      // column ownership (P1/P4/P10)
  const int rw   = wid;               // row-block ownership for fused L2+L3 (wid<7)

  // ---- hoisted weight fragments (W1, W4; W2/W3 live in LDS) ----
  s16x8 w1f[4], w4f;
  #pragma unroll
  for (int kt = 0; kt < 4; ++kt) w1f[kt] = packA8(&W1[colN*128 + kt*32 + 8*l4]);
  w4f = packA8(&W4[colN*32 + 8*l4]);
  const float bb1 = b1g[colN], bb4 = b4g[colN];
  float bb2v[4], bb3v[2];
  #pragma unroll
  for (int cg = 0; cg < 4; ++cg) bb2v[cg] = b2g[cg*16 + l15];
  #pragma unroll
  for (int cg = 0; cg < 2; ++cg) bb3v[cg] = b3g[cg*16 + l15];

  // ---- cov tile assignment (12 band tiles over 8 waves) ----
  const int mt1 = (0x22111000u >> (4*wid)) & 15;
  const int nt1 = (0x21210710u >> (4*wid)) & 15;
  const int mt2 = (0x3332u >> (4*wid)) & 15;   // valid for wid<4
  const int nt2 = (0x4323u >> (4*wid)) & 15;
  float tv1[4], tv2[4];
  #pragma unroll
  for (int i = 0; i < 4; ++i){
    tv1[i] = gc_taper(mt1*16 + 4*l4 + i, nt1*16 + l15);
    tv2[i] = (wid < 4) ? gc_taper(mt2*16 + 4*l4 + i, nt2*16 + l15) : 0.f;
  }

  // ---- systolic chol lane constants: 55 slots (dk,dd), dk in [0,9], dd in [0,9-dk]
  int cdk = 10, cdd = 0;
  { int acc = 0;
    #pragma unroll
    for (int q = 0; q < 10; ++q){
      int cnt = 10 - q;
      if (lane >= acc && lane < acc + cnt){ cdk = q; cdd = lane - acc; }
      acc += cnt;
    } }
  const int ioff_s  = (cdk + cdd > 9) ? 0 : (cdk + cdd);
  const int dk_s    = (cdk > 9) ? 0 : cdk;
  int baseNext = (cdk + 1)*10 - ((cdk + 1)*cdk)/2;
  const int shsrc   = (baseNext + cdd >= 55) ? 0 : (baseNext + cdd);
  const bool enterSlot = (cdk + cdd == 9) && (cdk <= 9);
  const bool isCol0    = (cdk == 0);

  // ---- stage W2/W3 to LDS as bf16 ----
  for (int idx = tid; idx < 64*128; idx += 512)
    sW2[(idx >> 7)*W2S + (idx & 127)] = f2bf(W2[idx]);
  for (int idx = tid; idx < 32*64; idx += 512)
    sW3[(idx >> 6)*W3S + (idx & 63)] = f2bf(W3[idx]);

  // ---- x0 into registers + bf16 mirror ----
  float xreg[7][4];
  {
    float qm = qmean[b*DXC + colN], qs = qstd[b*DXC + colN];
    #pragma unroll
    for (int m = 0; m < 7; ++m)
      #pragma unroll
      for (int i = 0; i < 4; ++i){
        int row = m*16 + 4*l4 + i;
        float v = 0.f;
        if (row < NMCC) v = qm + qs * eps0[((size_t)row*BC + b)*DXC + colN];
        xreg[m][i] = v;
        if (row < NMCC) sU[row*XBS + colN] = f2bf(v);
      }
    for (int idx = tid; idx < 12*128; idx += 512)
      sU[(100 + (idx >> 7))*XBS + (idx & 127)] = 0;
  }
  __syncthreads();

  float llsum = 0.f;
  const f32x4 z4 = {0.f, 0.f, 0.f, 0.f};

  for (int t = 0; t < TC; ++t){
    float ldet_t = 0.f;

    // y loads issued early (waves 0-3 own obs cols; consumed P4/P7)
    float y_r = 0.f, ypv = 0.f;
    if (wid < 4){
      y_r = obs[((size_t)b*TC + t)*DYC + colN];
      ypv = y_r + 0.1f*nsyg[((size_t)t*BC + b)*DYC + colN];
    }

    // eps(t) prefetch issued HERE; consumed in P4 (2 barriers of overlap)
    float ev[7][4];
    #pragma unroll
    for (int m = 0; m < 7; ++m)
      #pragma unroll
      for (int i = 0; i < 4; ++i){
        int row = m*16 + 4*l4 + i;
        ev[m][i] = (row < NMCC)
          ? epss[((size_t)(t*NMCC + row)*BC + b)*DXC + colN] : 0.f;
      }

    // ============ P1: MLP L1 (col-scheme) -> sA ============
    {
      f32x4 acc[7];
      #pragma unroll
      for (int m = 0; m < 7; ++m) acc[m] = z4;
      #pragma unroll
      for (int kt = 0; kt < 4; ++kt){
        #pragma unroll
        for (int m = 0; m < 7; ++m){
          s16x8 af = *(const s16x8*)&sU[(m*16 + l15)*XBS + kt*32 + 8*l4];
          acc[m] = mfma16(af, w1f[kt], acc[m]);
        }
      }
      #pragma unroll
      for (int m = 0; m < 7; ++m)
        #pragma unroll
        for (int i = 0; i < 4; ++i){
          int row = m*16 + 4*l4 + i;
          sA[row*A1S + colN] = f2bf(fmaxf(acc[m][i] + bb1, 0.f));
        }
    }
    __syncthreads();

    // ============ P2P3: fused MLP L2+L3 (row-scheme, wave rw<7, no inner barrier) ============
    if (rw < 7){
      // --- L2: rows 16rw..16rw+15, all 64 cols ---
      f32x4 a2[4];
      #pragma unroll
      for (int cg = 0; cg < 4; ++cg) a2[cg] = z4;
      #pragma unroll
      for (int kt = 0; kt < 4; ++kt){
        s16x8 af = *(const s16x8*)&sA[(16*rw + l15)*A1S + kt*32 + 8*l4];
        #pragma unroll
        for (int cg = 0; cg < 4; ++cg){
          s16x8 bf = *(const s16x8*)&sW2[(cg*16 + l15)*W2S + kt*32 + 8*l4];
          a2[cg] = mfma16(af, bf, a2[cg]);
        }
      }
      #pragma unroll
      for (int cg = 0; cg < 4; ++cg)
        #pragma unroll
        for (int i = 0; i < 4; ++i){
          int row = 16*rw + 4*l4 + i;
          sB[row*A2S + cg*16 + l15] = f2bf(fmaxf(a2[cg][i] + bb2v[cg], 0.f));
        }
      // --- L3: same rows, 32 cols; same-wave dep (lgkmcnt only) ---
      f32x4 a3[2];
      a3[0] = z4; a3[1] = z4;
      #pragma unroll
      for (int kt = 0; kt < 2; ++kt){
        s16x8 af3 = *(const s16x8*)&sB[(16*rw + l15)*A2S + kt*32 + 8*l4];
        #pragma unroll
        for (int cg = 0; cg < 2; ++cg){
          s16x8 bf = *(const s16x8*)&sW3[(cg*16 + l15)*W3S + kt*32 + 8*l4];
          a3[cg] = mfma16(af3, bf, a3[cg]);
        }
      }
      #pragma unroll
      for (int cg = 0; cg < 2; ++cg)
        #pragma unroll
        for (int i = 0; i < 4; ++i){
          int row = 16*rw + 4*l4 + i;
          sC[row*A3S + cg*16 + l15] = f2bf(fmaxf(a3[cg][i] + bb3v[cg], 0.f));
        }
    }
    __syncthreads();

    // ============ P4: L4 + eps -> xreg; in-reg mean; XcT pack; rv; innov(w0) ============
    {
      f32x4 acc[7];
      #pragma unroll
      for (int m = 0; m < 7; ++m) acc[m] = z4;
      #pragma unroll
      for (int m = 0; m < 7; ++m){
        s16x8 af = *(const s16x8*)&sC[(m*16 + l15)*A3S + 8*l4];
        acc[m] = mfma16(af, w4f, acc[m]);
      }
      float part = 0.f;
      #pragma unroll
      for (int m = 0; m < 7; ++m)
        #pragma unroll
        for (int i = 0; i < 4; ++i){
          int row = m*16 + 4*l4 + i;
          if (row < NMCC){
            float v = acc[m][i] + bb4 + 0.05f*ev[m][i];
            xreg[m][i] = v;
            part += v;
          } else xreg[m][i] = 0.f;
        }
      part += __shfl_xor(part, 16);
      part += __shfl_xor(part, 32);
      float xm = part * 0.01f;            // every lane of the column group has it
      if (l4 == 0) sXm[colN] = xm;
      if (wid < 4 && l4 == 0) sRv[colN] = y_r - xm;

      // XcT pack (cols needed by the cov band only)
      if (colN <= 72 || colN >= 119){
        #pragma unroll
        for (int m = 0; m < 7; ++m){
          float v0, v1, v2, v3;
          if (m == 6 && l4 > 0){ v0 = v1 = v2 = v3 = 0.f; }
          else {
            v0 = xreg[m][0] - xm; v1 = xreg[m][1] - xm;
            v2 = xreg[m][2] - xm; v3 = xreg[m][3] - xm;
          }
          uint2 pk;
          pk.x = pk2bf(v0, v1);
          pk.y = pk2bf(v2, v3);
          *(uint2*)&sU[colN*XBS + m*16 + 4*l4] = pk;
        }
        uint2 zz; zz.x = 0u; zz.y = 0u;
        *(uint2*)&sU[colN*XBS + 112 + 4*l4] = zz;
      }
      // innov pack for wave 0's columns (0..15); waves 1-3 do theirs in P7
      if (wid == 0){
        #pragma unroll
        for (int m = 0; m < 7; ++m)
          #pragma unroll
          for (int i = 0; i < 4; ++i){
            int row = m*16 + 4*l4 + i;
            sB[row*IVS + colN] = (row < NMCC) ? f2bf(ypv - xreg[m][i])
                                              : (unsigned short)0;
          }
      }
    }
    __syncthreads();

    // ============ P6: banded cov tiles: HP = taper .* (XcT@Xc) ============
    {
      f32x4 a1 = z4, a2 = z4;
      #pragma unroll
      for (int kt = 0; kt < 4; ++kt){
        s16x8 fa1 = *(const s16x8*)&sU[(mt1*16 + l15)*XBS + kt*32 + 8*l4];
        s16x8 fb1 = *(const s16x8*)&sU[(nt1*16 + l15)*XBS + kt*32 + 8*l4];
        a1 = mfma16(fa1, fb1, a1);
        if (wid < 4){
          s16x8 fa2 = *(const s16x8*)&sU[(mt2*16 + l15)*XBS + kt*32 + 8*l4];
          s16x8 fb2 = *(const s16x8*)&sU[(nt2*16 + l15)*XBS + kt*32 + 8*l4];
          a2 = mfma16(fa2, fb2, a2);
        }
      }
      #pragma unroll
      for (int i = 0; i < 4; ++i){
        int o = mt1*16 + 4*l4 + i, e = nt1*16 + l15;
        float v = a1[i] * tv1[i];
        if (nt1 != 7){
          int dd = e - o;
          if (dd >= -9 && dd <= 9) sHPb[o*HPS + dd + 9] = v;
        } else {
          int w = e - 119;
          if (w >= 0 && o <= w) sW9[o*12 + w] = v;
        }
      }
      if (wid < 4){
        #pragma unroll
        for (int i = 0; i < 4; ++i){
          int o = mt2*16 + 4*l4 + i, e = nt2*16 + l15;
          float v = a2[i] * tv2[i];
          int dd = e - o;
          if (dd >= -9 && dd <= 9) sHPb[o*HPS + dd + 9] = v;
        }
      }
    }
    __syncthreads();

    // ============ P7: chol (w0, register-systolic, setprio) ∥ innov (w1-3) ============
    if (wid == 0){
      __builtin_amdgcn_s_setprio(1);
      float v = 0.f;
      if (cdk <= 9) v = sHPb[cdk*HPS + cdd + 9] + ((cdd == 0) ? 0.01f : 0.f);
      for (int j = 0; j < 64; ++j){
        float enter = 0.f;
        if (enterSlot && (j + 10 < 64))
          enter = sHPb[(j + 10 - cdd)*HPS + cdd + 9] + ((cdd == 0) ? 0.01f : 0.f);
        float upiv = __shfl(v, 0);
        float u1   = __shfl(v, ioff_s);
        float u2   = __shfl(v, dk_s);
        float rd   = rsqrtf(upiv);
        float rpiv = rd * rd;
        if (isCol0){
          sLb[j*LBS + cdd] = (cdd == 0) ? rd : v * rd;
        }
        if (lane == 0) ldet_t += 0.5f * logf(upiv);
        float vu = (cdk >= 1) ? v - u1*u2*rpiv : v;
        float vs = __shfl(vu, shsrc);
        v = enterSlot ? enter : vs;
      }
      __builtin_amdgcn_s_setprio(0);
    } else if (wid < 4){
      // innovation pack for cols 16..63
      #pragma unroll
      for (int m = 0; m < 7; ++m)
        #pragma unroll
        for (int i = 0; i < 4; ++i){
          int row = m*16 + 4*l4 + i;
          sB[row*IVS + colN] = (row < NMCC) ? f2bf(ypv - xreg[m][i])
                                            : (unsigned short)0;
        }
    }
    __syncthreads();

    // ============ P8: band solves (83 RHS) -> KT bf16, means, ll ============
    {
      float* zscr = (float*)sU;                       // XcT dead; Xbf rewritten in P10
      unsigned short* KT = (unsigned short*)sA;       // acts1 dead
      int c = tid;
      if (c < 83){
        int e = (c < 73) ? c : (c + 46);              // 73..81 -> 119..127
        bool isr = (c == 82);
        float w0,w1,w2,w3,w4,w5,w6,w7,w8,w9;
        {
          float wi[10];
          #pragma unroll
          for (int d = 0; d < 10; ++d){
            float bv = 0.f;
            if (isr) bv = sRv[d];
            else if (c < 73){
              int idx = e - d + 9;
              if (idx >= 0 && idx <= 18) bv = sHPb[d*HPS + idx];
            } else {
              int ww = e - 119;
              if (d <= ww) bv = sW9[d*12 + ww];
            }
            wi[d] = bv;
          }
          w0=wi[0]; w1=wi[1]; w2=wi[2]; w3=wi[3]; w4=wi[4];
          w5=wi[5]; w6=wi[6]; w7=wi[7]; w8=wi[8]; w9=wi[9];
        }
        // forward solve, Lb prefetched one iteration ahead
        float z2l = 0.f;
        f32x4 lb0 = *(const f32x4*)&sLb[0];
        f32x4 lb4 = *(const f32x4*)&sLb[4];
        float2 l89 = *(const float2*)&sLb[8];
        for (int j = 0; j < 64; ++j){
          f32x4 nb0 = lb0, nb4 = lb4; float2 n89 = l89;
          if (j + 1 < 64){
            nb0 = *(const f32x4*)&sLb[(j+1)*LBS];
            nb4 = *(const f32x4*)&sLb[(j+1)*LBS + 4];
            n89 = *(const float2*)&sLb[(j+1)*LBS + 8];
          }
          float z = w0 * lb0[0];
          zscr[c*ZSS + j] = z;
          z2l += z*z;
          w0 = w1 - lb0[1]*z; w1 = w2 - lb0[2]*z; w2 = w3 - lb0[3]*z;
          w3 = w4 - lb4[0]*z; w4 = w5 - lb4[1]*z; w5 = w6 - lb4[2]*z;
          w6 = w7 - lb4[3]*z; w7 = w8 - l89.x*z;  w8 = w9 - l89.y*z;
          int jn = j + 10;
          float bv = 0.f;
          if (isr){ if (jn < 64) bv = sRv[jn]; }
          else if (c < 73){
            if (jn < 64 && j >= e - 19 && j <= e - 1) bv = sHPb[jn*HPS + (e - j - 1)];
          }
          w9 = bv;
          lb0 = nb0; lb4 = nb4; l89 = n89;
        }
        if (isr) sSc[0] = z2l;
        // backward solve, Lb + z prefetched one iteration ahead
        float x1=0.f,x2=0.f,x3=0.f,x4=0.f,x5=0.f,x6=0.f,x7=0.f,x8=0.f,x9=0.f;
        float macc = 0.f, xodd = 0.f;
        lb0 = *(const f32x4*)&sLb[63*LBS];
        lb4 = *(const f32x4*)&sLb[63*LBS + 4];
        l89 = *(const float2*)&sLb[63*LBS + 8];
        float zcur = zscr[c*ZSS + 63];
        for (int j = 63; j >= 0; --j){
          f32x4 nb0 = lb0, nb4 = lb4; float2 n89 = l89;
          float znext = zcur;
          if (j > 0){
            nb0 = *(const f32x4*)&sLb[(j-1)*LBS];
            nb4 = *(const f32x4*)&sLb[(j-1)*LBS + 4];
            n89 = *(const float2*)&sLb[(j-1)*LBS + 8];
            znext = zscr[c*ZSS + j - 1];
          }
          float acc = zcur
            - lb0[1]*x1 - lb0[2]*x2 - lb0[3]*x3
            - lb4[0]*x4 - lb4[1]*x5 - lb4[2]*x6 - lb4[3]*x7
            - l89.x*x8 - l89.y*x9;
          float xj = acc * lb0[0];
          if (!isr){
            macc += sRv[j]*xj;
            if (j & 1) xodd = xj;
            else *(unsigned int*)&KT[e*KTS + j] = pk2bf(xj, xodd);
          }
          x9=x8; x8=x7; x7=x6; x6=x5; x5=x4; x4=x3; x3=x2; x2=x1; x1=xj;
          lb0 = nb0; lb4 = nb4; l89 = n89; zcur = znext;
        }
        if (!isr) out_means[((size_t)t*BC + b)*DXC + e] = sXm[e] + macc;
      } else if (c < 129){
        int e = c - 10;                               // cols 73..118: K is zero
        out_means[((size_t)t*BC + b)*DXC + e] = sXm[e];
      }
    }
    __syncthreads();

    // ============ P10: ll ; update xreg += innov @ K ; rewrite Xbf ============
    if (tid == 0){
      llsum += -0.5f*sSc[0] - ldet_t - 58.812066f;    // 0.5*DY*log(2*pi)
    }
    {
      f32x4 uacc[7];
      #pragma unroll
      for (int m = 0; m < 7; ++m) uacc[m] = z4;
      if (wid != 5 && wid != 6){
        const unsigned short* KT = (const unsigned short*)sA;
        #pragma unroll
        for (int kt = 0; kt < 2; ++kt){
          s16x8 bf = *(const s16x8*)&KT[colN*KTS + kt*32 + 8*l4];
          #pragma unroll
          for (int m = 0; m < 7; ++m){
            s16x8 af = *(const s16x8*)&sB[(m*16 + l15)*IVS + kt*32 + 8*l4];
            uacc[m] = mfma16(af, bf, uacc[m]);
          }
        }
      }
      bool upd = ((colN <= 72) || (colN >= 119)) && (wid != 5) && (wid != 6);
      #pragma unroll
      for (int m = 0; m < 7; ++m)
        #pragma unroll
        for (int i = 0; i < 4; ++i){
          int row = m*16 + 4*l4 + i;
          if (row < NMCC){
            float xn = xreg[m][i] + (upd ? uacc[m][i] : 0.f);
            xreg[m][i] = xn;
            sU[row*XBS + colN] = f2bf(xn);
          }
        }
    }
    __syncthreads();
  } // t loop

  if (tid == 0) llp[b] = llsum;
}

// ---------------- final: elbo = -mean(kl) + sum_t mean_b ll ----------------
__global__ void final_kernel(const float* __restrict__ klp, const float* __restrict__ llp,
                             float* __restrict__ out){
  __shared__ float s1[128], s2[128];
  int tid = threadIdx.x;
  s1[tid] = klp[tid];
  s2[tid] = llp[tid];
  __syncthreads();
  if (tid == 0){
    float a = 0.f, c = 0.f;
    for (int i = 0; i < 128; ++i){ a += s1[i]; c += s2[i]; }
    out[0] = -a/128.f + c/128.f;
  }
}

extern "C" void kernel_launch(void* const* d_in, const int* in_sizes, int n_in,
                              void* d_out, int out_size, void* d_ws, size_t ws_size,
                              hipStream_t stream){
  (void)in_sizes; (void)n_in; (void)out_size; (void)ws_size;
  const float* obs  = (const float*)d_in[0];
  const float* W1   = (const float*)d_in[1];
  const float* b1   = (const float*)d_in[2];
  const float* W2   = (const float*)d_in[3];
  const float* b2   = (const float*)d_in[4];
  const float* W3   = (const float*)d_in[5];
  const float* b3   = (const float*)d_in[6];
  const float* W4   = (const float*)d_in[7];
  const float* b4   = (const float*)d_in[8];
  const float* Wih  = (const float*)d_in[9];
  const float* Whh  = (const float*)d_in[10];
  const float* bih  = (const float*)d_in[11];
  const float* Wm   = (const float*)d_in[12];
  const float* bm   = (const float*)d_in[13];
  const float* Wv   = (const float*)d_in[14];
  const float* bv   = (const float*)d_in[15];
  const float* eps0 = (const float*)d_in[16];
  const float* epss = (const float*)d_in[17];
  const float* nsy  = (const float*)d_in[18];

  char* ws = (char*)d_ws;
  float* gin   = (float*)(ws + 0);           // 50*128*256*4 = 6,553,600 B
  float* qmean = (float*)(ws + 6553600);
  float* qstd  = (float*)(ws + 6619136);
  float* klp   = (float*)(ws + 6684672);
  float* llp   = (float*)(ws + 6685184);

  float* out = (float*)d_out;

  hipLaunchKernelGGL(gin_kernel, dim3(TC*BC), dim3(256), 0, stream,
                     obs, Wih, bih, gin);
  hipLaunchKernelGGL(lstm_kernel, dim3(BC), dim3(256), 0, stream,
                     gin, Whh, Wm, bm, Wv, bv, qmean, qstd, klp);
  hipLaunchKernelGGL(enkf_kernel, dim3(BC), dim3(512), 0, stream,
                     obs, W1, b1, W2, b2, W3, b3, W4, b4,
                     eps0, epss, nsy, qmean, qstd, out + 1, llp);
  hipLaunchKernelGGL(final_kernel, dim3(1), dim3(128), 0, stream, klp, llp, out);
}